// Round 2
// baseline (1936.606 us; speedup 1.0000x reference)
//
#include <hip/hip_runtime.h>
#include <cstdint>

#define BATCH 4
#define DIMC 384
#define CINC 387
#define COMPC 64
#define GSZ 224

typedef __attribute__((ext_vector_type(8))) short bf16x8;
typedef __attribute__((ext_vector_type(4))) short s16x4;
typedef __attribute__((ext_vector_type(4))) float f32x4;

static __device__ __forceinline__ unsigned short f2bf(float x) {
  unsigned int u = __float_as_uint(x);
  unsigned int r = (u + 0x7fffu + ((u >> 16) & 1u)) >> 16;
  return (unsigned short)r;
}
static __device__ __forceinline__ float bf2f(unsigned short b) {
  return __uint_as_float(((unsigned int)b) << 16);
}
// split x into bf16 hi + bf16 lo (rne both; x ~= hi + lo)
static __device__ __forceinline__ void cvt2(float x, unsigned short& h, unsigned short& l) {
  unsigned int u = __float_as_uint(x);
  unsigned int hb = (u + 0x7fffu + ((u >> 16) & 1u)) >> 16;
  h = (unsigned short)hb;
  float r = x - __uint_as_float(hb << 16);
  unsigned int u2 = __float_as_uint(r);
  l = (unsigned short)((u2 + 0x7fffu + ((u2 >> 16) & 1u)) >> 16);
}

// ---------- antialiased bilinear resize (jax.image.resize, antialias=True) ----------
__global__ void resize_kernel(const float* __restrict__ g, float* __restrict__ out,
                              int h, int w, int inv_scale) {
  int idx = blockIdx.x * blockDim.x + threadIdx.x;
  int total = BATCH * 3 * h * w;
  if (idx >= total) return;
  int j = idx % w; int t = idx / w;
  int i = t % h; t /= h;
  float ks = (float)inv_scale;
  float sy = (i + 0.5f) * ks - 0.5f;
  float sx = (j + 0.5f) * ks - 0.5f;
  int y0 = (int)ceilf(sy - ks); if (y0 < 0) y0 = 0;
  int y1 = (int)floorf(sy + ks); if (y1 > GSZ - 1) y1 = GSZ - 1;
  int x0 = (int)ceilf(sx - ks); if (x0 < 0) x0 = 0;
  int x1 = (int)floorf(sx + ks); if (x1 > GSZ - 1) x1 = GSZ - 1;
  const float* gp = g + (size_t)t * GSZ * GSZ;
  float wsx = 0.f;
  for (int x = x0; x <= x1; ++x) wsx += fmaxf(0.f, 1.f - fabsf(sx - (float)x) / ks);
  float acc = 0.f, wsy = 0.f;
  for (int y = y0; y <= y1; ++y) {
    float wy = fmaxf(0.f, 1.f - fabsf(sy - (float)y) / ks);
    wsy += wy;
    if (wy > 0.f) {
      const float* rp = gp + (size_t)y * GSZ;
      float row = 0.f;
      for (int x = x0; x <= x1; ++x) {
        float wx = fmaxf(0.f, 1.f - fabsf(sx - (float)x) / ks);
        row += wx * rp[x];
      }
      acc += wy * row;
    }
  }
  out[idx] = acc / (wsx * wsy);
}

// ---------- weight prep ----------
__global__ void prep_cw(const float* __restrict__ c0, const float* __restrict__ c1,
                        const float* __restrict__ c2, const float* __restrict__ c3,
                        float* __restrict__ cwT) {
  int s = blockIdx.y;
  const float* cw = (s == 0) ? c0 : (s == 1) ? c1 : (s == 2) ? c2 : c3;
  int idx = blockIdx.x * 256 + threadIdx.x;
  if (idx >= CINC * COMPC) return;
  int ci = idx >> 6, co = idx & 63;
  cwT[s * (CINC * COMPC) + idx] = cw[co * CINC + ci];
}

// ewT2 layout: [s][pos][ci][tap][12]  (k padded 9->12 for float4 alignment)
#define EW2_PER_S (4 * COMPC * 9 * 12)
__global__ void prep_ew(const float* __restrict__ e0, const float* __restrict__ e1,
                        const float* __restrict__ e2, const float* __restrict__ e3,
                        float* __restrict__ ewT2) {
  int s = blockIdx.y;
  const float* ew = (s == 0) ? e0 : (s == 1) ? e1 : (s == 2) ? e2 : e3;
  int idx = blockIdx.x * 256 + threadIdx.x;
  if (idx >= EW2_PER_S) return;
  int k = idx % 12; int r = idx / 12;
  int tap = r % 9; r /= 9;
  int ci = r % COMPC; int pos = r / COMPC;
  float val = 0.f;
  if (k < 9) val = ew[(size_t)(k * 4 + pos) * (COMPC * 9) + ci * 9 + tap];
  ewT2[(size_t)s * EW2_PER_S + idx] = val;
}

#define KPAD 416
__global__ void prep_w(const float* __restrict__ pw, short* __restrict__ Whi,
                       short* __restrict__ Wlo) {
  int idx = blockIdx.x * 256 + threadIdx.x;
  if (idx >= DIMC * KPAD) return;
  int co = idx / KPAD, k = idx % KPAD;
  float v = (k < CINC) ? pw[co * CINC + k] : 0.f;
  unsigned short hb = f2bf(v);
  Whi[idx] = (short)hb;
  Wlo[idx] = (short)f2bf(v - bf2f(hb));
}

// ---------- 1x1 conv 387->64 v2: 4 px x 4 co per thread ----------
// blockIdx.y = co-group (16 groups of 4 co) -> weight/bias loads are wave-uniform
// (scalar path); lanes cover consecutive px quads -> 1KB contiguous per wave load.
// Load:FMA = 2 VMEM : 16 FMA per ci (was 2:4).
__global__ void comp_conv_kernel(const float* __restrict__ src, const float* __restrict__ g,
                                 const float* __restrict__ cwT, const float* __restrict__ cb,
                                 float* __restrict__ comp, int h, int w) {
  int hw = h * w;
  int hw4 = hw >> 2;
  int q = blockIdx.x * 256 + threadIdx.x;
  if (q >= hw4) return;
  int co0 = blockIdx.y * 4;
  int n = blockIdx.z;
  float4 b = *(const float4*)&cb[co0];
  float acc[4][4];
  #pragma unroll
  for (int px = 0; px < 4; ++px) { acc[0][px] = b.x; acc[1][px] = b.y; acc[2][px] = b.z; acc[3][px] = b.w; }
  const float* sp = src + (size_t)n * DIMC * hw + q * 4;
  for (int ci = 0; ci < DIMC; ++ci) {
    float4 v = *(const float4*)(sp + (size_t)ci * hw);
    float4 wv = *(const float4*)&cwT[ci * COMPC + co0];
    acc[0][0] += wv.x * v.x; acc[0][1] += wv.x * v.y; acc[0][2] += wv.x * v.z; acc[0][3] += wv.x * v.w;
    acc[1][0] += wv.y * v.x; acc[1][1] += wv.y * v.y; acc[1][2] += wv.y * v.z; acc[1][3] += wv.y * v.w;
    acc[2][0] += wv.z * v.x; acc[2][1] += wv.z * v.y; acc[2][2] += wv.z * v.z; acc[2][3] += wv.z * v.w;
    acc[3][0] += wv.w * v.x; acc[3][1] += wv.w * v.y; acc[3][2] += wv.w * v.z; acc[3][3] += wv.w * v.w;
  }
  const float* gp = g + (size_t)n * 3 * hw + q * 4;
  #pragma unroll
  for (int ci = 0; ci < 3; ++ci) {
    float4 v = *(const float4*)(gp + (size_t)ci * hw);
    float4 wv = *(const float4*)&cwT[(DIMC + ci) * COMPC + co0];
    acc[0][0] += wv.x * v.x; acc[0][1] += wv.x * v.y; acc[0][2] += wv.x * v.z; acc[0][3] += wv.x * v.w;
    acc[1][0] += wv.y * v.x; acc[1][1] += wv.y * v.y; acc[1][2] += wv.y * v.z; acc[1][3] += wv.y * v.w;
    acc[2][0] += wv.z * v.x; acc[2][1] += wv.z * v.y; acc[2][2] += wv.z * v.z; acc[2][3] += wv.z * v.w;
    acc[3][0] += wv.w * v.x; acc[3][1] += wv.w * v.y; acc[3][2] += wv.w * v.z; acc[3][3] += wv.w * v.w;
  }
  float* op = comp + (size_t)n * COMPC * hw + q * 4;
  #pragma unroll
  for (int c = 0; c < 4; ++c) {
    float4 r; r.x = acc[c][0]; r.y = acc[c][1]; r.z = acc[c][2]; r.w = acc[c][3];
    *(float4*)(op + (size_t)(co0 + c) * hw) = r;
  }
}

// ---------- 3x3 conv 64->36 + pixel_shuffle + softmax, v2 ----------
// thread = (pos from blockIdx.y, 4-px x-strip). Weights from aligned [pos][ci][tap][12]
// table: 2 float4 + 1 scalar per tap, uniform per block. v loads shared over 4 px.
// Load:FMA per ci: ~45:324 (was ~10:9 per px-pos).
__global__ void enc_mask_kernel(const float* __restrict__ comp, const float* __restrict__ ewT2,
                                const float* __restrict__ eb, float* __restrict__ mask,
                                int h, int w) {
  int hw = h * w;
  int sw4 = (w + 3) >> 2;
  int nstrip = h * sw4;
  int strip = blockIdx.x * 256 + threadIdx.x;
  if (strip >= nstrip) return;
  int pos = blockIdx.y;
  int n = blockIdx.z;
  int i = strip / sw4;
  int j0 = (strip - i * sw4) * 4;
  float acc[4][9];
  #pragma unroll
  for (int k = 0; k < 9; ++k) {
    float bv = eb[k * 4 + pos];
    #pragma unroll
    for (int px = 0; px < 4; ++px) acc[px][k] = bv;
  }
  const float* cpn = comp + (size_t)n * COMPC * hw;
  const float* wpos = ewT2 + (size_t)pos * COMPC * 9 * 12;
  for (int ci = 0; ci < COMPC; ++ci) {
    const float* cp = cpn + (size_t)ci * hw;
    float v[3][6];
    #pragma unroll
    for (int di = 0; di < 3; ++di) {
      int y = i + di - 1;
      bool yok = (y >= 0 && y < h);
      #pragma unroll
      for (int xx = 0; xx < 6; ++xx) {
        int x = j0 - 1 + xx;
        v[di][xx] = (yok && x >= 0 && x < w) ? cp[(size_t)y * w + x] : 0.f;
      }
    }
    const float* wb = wpos + (size_t)ci * 9 * 12;
    #pragma unroll
    for (int tap = 0; tap < 9; ++tap) {
      int di = tap / 3, dj = tap % 3;
      float4 wa = *(const float4*)(wb + tap * 12);
      float4 wc = *(const float4*)(wb + tap * 12 + 4);
      float w8 = wb[tap * 12 + 8];
      #pragma unroll
      for (int px = 0; px < 4; ++px) {
        float val = v[di][dj + px];
        acc[px][0] += wa.x * val; acc[px][1] += wa.y * val;
        acc[px][2] += wa.z * val; acc[px][3] += wa.w * val;
        acc[px][4] += wc.x * val; acc[px][5] += wc.y * val;
        acc[px][6] += wc.z * val; acc[px][7] += wc.w * val;
        acc[px][8] += w8 * val;
      }
    }
  }
  int pp = pos >> 1, q = pos & 1;
  int H = 2 * h, W = 2 * w;
  #pragma unroll
  for (int px = 0; px < 4; ++px) {
    int jj = j0 + px;
    if (jj >= w) continue;
    float m = -1e30f;
    #pragma unroll
    for (int k = 0; k < 9; ++k) m = fmaxf(m, acc[px][k]);
    float e[9]; float s = 0.f;
    #pragma unroll
    for (int k = 0; k < 9; ++k) { e[k] = __expf(acc[px][k] - m); s += e[k]; }
    float inv = 1.f / s;
    float* mp = mask + (((size_t)n * H + (2 * i + pp)) * W + (2 * jj + q)) * 9;
    #pragma unroll
    for (int k = 0; k < 9; ++k) mp[k] = e[k] * inv;
  }
}

// ---------- CARAFE reassembly: 16 channels per thread ----------
__global__ void carafe_kernel(const float* __restrict__ src, const float* __restrict__ mask,
                              float* __restrict__ out, int h, int w) {
  int p = blockIdx.x * blockDim.x + threadIdx.x;
  int hw = h * w;
  if (p >= hw) return;
  int c0 = blockIdx.y * 16, n = blockIdx.z;
  int i = p / w, j = p % w;
  int H = 2 * h, W = 2 * w;
  float m[4][9];
  #pragma unroll
  for (int pp = 0; pp < 2; ++pp)
    #pragma unroll
    for (int q = 0; q < 2; ++q) {
      const float* mp = mask + (((size_t)n * H + (2 * i + pp)) * W + (2 * j + q)) * 9;
      #pragma unroll
      for (int k = 0; k < 9; ++k) m[pp * 2 + q][k] = mp[k];
    }
  for (int cc = 0; cc < 16; ++cc) {
    int c = c0 + cc;
    const float* sp = src + ((size_t)(n * DIMC + c)) * hw;
    float v[9];
    #pragma unroll
    for (int k = 0; k < 9; ++k) {
      int y = i - 1 + k / 3, x = j - 1 + k % 3;
      v[k] = (y >= 0 && y < h && x >= 0 && x < w) ? sp[(size_t)y * w + x] : 0.f;
    }
    float* op = out + ((size_t)(n * DIMC + c)) * H * W;
    #pragma unroll
    for (int pp = 0; pp < 2; ++pp) {
      float a0 = 0.f, a1 = 0.f;
      #pragma unroll
      for (int k = 0; k < 9; ++k) {
        a0 += v[k] * m[pp * 2 + 0][k];
        a1 += v[k] * m[pp * 2 + 1][k];
      }
      float2 r; r.x = a0; r.y = a1;
      *(float2*)(op + (size_t)(2 * i + pp) * W + 2 * j) = r;
    }
  }
}

// ---------- final 1x1 conv 387->384 via bf16x3 MFMA, v3 ----------
// v2 post-mortem: vmcnt is IN-ORDER; X prefetch issued BEFORE the weight loads means
// the MFMA's weight-wait retires the X loads in the SAME iteration -> zero effective
// prefetch depth, HBM latency on the critical path every kt. v3: depth-2 prefetch
// issued AFTER the MFMA/weight cluster (sched_barrier(0) pins the order): chunk c is
// issued at iter c-2, LDS-written at iter c-1, consumed at iter c. One barrier per kt.
__global__ __launch_bounds__(512, 4) void final_conv_mfma3(
    const float* __restrict__ guid, const short* __restrict__ Whi,
    const short* __restrict__ Wlo, const float* __restrict__ pb,
    float* __restrict__ out) {
  __shared__ short XH[2][2048];
  __shared__ short XL[2][2048];
  const int HW = GSZ * GSZ;
  const int n = blockIdx.y;
  const int px0 = blockIdx.x * 64;
  const int tid = threadIdx.x;
  const int wv = tid >> 6;
  const int lane = tid & 63;
  const int lm = lane & 15, qq = lane >> 4;

  // staging: thread (wv, lane) stages element (k_local = wv*4+i, px = lane)
  const int s_nt = lane >> 4, s_lm = lane & 15;
  const int s_qq = wv >> 1;
  const int s_jh = (wv & 1) * 4;
  const int waddr = ((s_nt * 4 + s_qq) * 16 + s_lm) * 8 + s_jh;

  const float* Xb = out + (size_t)n * DIMC * HW + px0 + lane;
  const float* Gb = guid + (size_t)n * 3 * HW + px0 + lane;

  f32x4 acc[3][4];
  #pragma unroll
  for (int mt = 0; mt < 3; ++mt)
    #pragma unroll
    for (int nt = 0; nt < 4; ++nt) acc[mt][nt] = (f32x4){0.f, 0.f, 0.f, 0.f};

  // prologue: chunk 0 -> buf0; chunk 1 -> regs (written during kt=0)
  float nvA[4];
  {
    unsigned short hs[4], ls[4];
    #pragma unroll
    for (int i = 0; i < 4; ++i) {
      float v = Xb[(size_t)(wv * 4 + i) * HW];
      cvt2(v, hs[i], ls[i]);
    }
    *(s16x4*)&XH[0][waddr] = (s16x4){(short)hs[0], (short)hs[1], (short)hs[2], (short)hs[3]};
    *(s16x4*)&XL[0][waddr] = (s16x4){(short)ls[0], (short)ls[1], (short)ls[2], (short)ls[3]};
    #pragma unroll
    for (int i = 0; i < 4; ++i) nvA[i] = Xb[(size_t)(32 + wv * 4 + i) * HW];
  }
  __syncthreads();

  for (int kt = 0; kt < 13; ++kt) {
    const int cur = kt & 1;
    // ---- B fragments from LDS ----
    bf16x8 bh[4], bl[4];
    #pragma unroll
    for (int nt = 0; nt < 4; ++nt) {
      int a = ((nt * 4 + qq) * 16 + lm) * 8;
      bh[nt] = *(const bf16x8*)&XH[cur][a];
      bl[nt] = *(const bf16x8*)&XL[cur][a];
    }
    // ---- weights (L2) + MFMA cluster ----
    #pragma unroll
    for (int mt = 0; mt < 3; ++mt) {
      int co = wv * 48 + mt * 16 + lm;
      size_t woff = (size_t)co * KPAD + kt * 32 + qq * 8;
      bf16x8 ah = *(const bf16x8*)(Whi + woff);
      bf16x8 al = *(const bf16x8*)(Wlo + woff);
      #pragma unroll
      for (int nt = 0; nt < 4; ++nt) {
        acc[mt][nt] = __builtin_amdgcn_mfma_f32_16x16x32_bf16(ah, bh[nt], acc[mt][nt], 0, 0, 0);
        acc[mt][nt] = __builtin_amdgcn_mfma_f32_16x16x32_bf16(ah, bl[nt], acc[mt][nt], 0, 0, 0);
        acc[mt][nt] = __builtin_amdgcn_mfma_f32_16x16x32_bf16(al, bh[nt], acc[mt][nt], 0, 0, 0);
      }
    }
    // keep the prefetch AFTER the weight loads in issue order (in-order vmcnt!)
    __builtin_amdgcn_sched_barrier(0);
    // ---- issue chunk kt+2 (retires during iteration kt+1) ----
    float nvB[4] = {0.f, 0.f, 0.f, 0.f};
    if (kt <= 10) {
      int kb = (kt + 2) * 32 + wv * 4;
      if (kt < 10) {
        #pragma unroll
        for (int i = 0; i < 4; ++i) nvB[i] = Xb[(size_t)(kb + i) * HW];
      } else {  // chunk 12: guidance rows 384..386 + zero pad
        #pragma unroll
        for (int i = 0; i < 4; ++i) {
          int k = kb + i;
          nvB[i] = (k < CINC) ? Gb[(size_t)(k - DIMC) * HW] : 0.f;
        }
      }
    }
    // ---- write chunk kt+1 (loaded at iter kt-1) into the other buffer ----
    if (kt <= 11) {
      unsigned short hs[4], ls[4];
      #pragma unroll
      for (int i = 0; i < 4; ++i) cvt2(nvA[i], hs[i], ls[i]);
      *(s16x4*)&XH[cur ^ 1][waddr] = (s16x4){(short)hs[0], (short)hs[1], (short)hs[2], (short)hs[3]};
      *(s16x4*)&XL[cur ^ 1][waddr] = (s16x4){(short)ls[0], (short)ls[1], (short)ls[2], (short)ls[3]};
    }
    __syncthreads();
    #pragma unroll
    for (int i = 0; i < 4; ++i) nvA[i] = nvB[i];
  }

  #pragma unroll
  for (int mt = 0; mt < 3; ++mt) {
    #pragma unroll
    for (int nt = 0; nt < 4; ++nt) {
      #pragma unroll
      for (int r = 0; r < 4; ++r) {
        int co = wv * 48 + mt * 16 + qq * 4 + r;
        int px = px0 + nt * 16 + lm;
        out[((size_t)(n * DIMC + co)) * HW + px] = acc[mt][nt][r] + pb[co];
      }
    }
  }
}

extern "C" void kernel_launch(void* const* d_in, const int* in_sizes, int n_in,
                              void* d_out, int out_size, void* d_ws, size_t ws_size,
                              hipStream_t stream) {
  const float* source   = (const float*)d_in[0];
  const float* guidance = (const float*)d_in[1];
  const float* cw[4] = {(const float*)d_in[2],  (const float*)d_in[6],
                        (const float*)d_in[10], (const float*)d_in[14]};
  const float* cb[4] = {(const float*)d_in[3],  (const float*)d_in[7],
                        (const float*)d_in[11], (const float*)d_in[15]};
  const float* ew[4] = {(const float*)d_in[4],  (const float*)d_in[8],
                        (const float*)d_in[12], (const float*)d_in[16]};
  const float* eb[4] = {(const float*)d_in[5],  (const float*)d_in[9],
                        (const float*)d_in[13], (const float*)d_in[17]};
  const float* pw = (const float*)d_in[18];
  const float* pb = (const float*)d_in[19];
  float* out = (float*)d_out;

  float* ws = (float*)d_ws;
  float* g_buf    = ws;                     // 4*3*112*112        = 150528
  float* comp_buf = g_buf + 150528;         // 4*64*112*112       = 3211264
  float* mask_buf = comp_buf + 3211264;     // 4*224*224*9        = 1806336
  float* s2  = mask_buf + 1806336;          // 4*384*28*28        = 1204224
  float* s4  = s2 + 1204224;                // 4*384*56*56        = 4816896
  float* s8  = s4 + 4816896;                // 4*384*112*112      = 19267584
  float* cwT = s8 + 19267584;               // 4*387*64           = 99072
  float* ewT2 = cwT + 99072;                // 4*27648            = 110592
  short* Whi = (short*)(ewT2 + 110592);     // 384*416 shorts
  short* Wlo = Whi + DIMC * KPAD;

  prep_cw<<<dim3((CINC * COMPC + 255) / 256, 4), 256, 0, stream>>>(cw[0], cw[1], cw[2], cw[3], cwT);
  prep_ew<<<dim3((EW2_PER_S + 255) / 256, 4), 256, 0, stream>>>(ew[0], ew[1], ew[2], ew[3], ewT2);
  prep_w<<<(DIMC * KPAD + 255) / 256, 256, 0, stream>>>(pw, Whi, Wlo);

  const float* srcs[4] = {source, s2, s4, s8};
  float* outs[4] = {s2, s4, s8, out};
  const int hs[4] = {14, 28, 56, 112};
  for (int s = 0; s < 4; ++s) {
    int h = hs[s], w = h, hw = h * w;
    int total_r = BATCH * 3 * hw;
    int hw4 = hw / 4;
    int sw4 = (w + 3) / 4;
    resize_kernel<<<(total_r + 255) / 256, 256, 0, stream>>>(guidance, g_buf, h, w, GSZ / h);
    comp_conv_kernel<<<dim3((hw4 + 255) / 256, 16, BATCH), 256, 0, stream>>>(
        srcs[s], g_buf, cwT + s * (CINC * COMPC), cb[s], comp_buf, h, w);
    enc_mask_kernel<<<dim3((h * sw4 + 255) / 256, 4, BATCH), 256, 0, stream>>>(
        comp_buf, ewT2 + (size_t)s * EW2_PER_S, eb[s], mask_buf, h, w);
    carafe_kernel<<<dim3((hw + 255) / 256, DIMC / 16, BATCH), 256, 0, stream>>>(
        srcs[s], mask_buf, outs[s], h, w);
  }
  final_conv_mfma3<<<dim3((GSZ * GSZ) / 64, BATCH), 512, 0, stream>>>(guidance, Whi, Wlo, pb, out);
}

// Round 3
// 1643.939 us; speedup vs baseline: 1.1780x; 1.1780x over previous
//
#include <hip/hip_runtime.h>
#include <cstdint>

#define BATCH 4
#define DIMC 384
#define CINC 387
#define COMPC 64
#define GSZ 224

typedef __attribute__((ext_vector_type(8))) short bf16x8;
typedef __attribute__((ext_vector_type(4))) short s16x4;
typedef __attribute__((ext_vector_type(4))) float f32x4;

static __device__ __forceinline__ unsigned short f2bf(float x) {
  unsigned int u = __float_as_uint(x);
  unsigned int r = (u + 0x7fffu + ((u >> 16) & 1u)) >> 16;
  return (unsigned short)r;
}
static __device__ __forceinline__ float bf2f(unsigned short b) {
  return __uint_as_float(((unsigned int)b) << 16);
}
// split x into bf16 hi + bf16 lo (rne both; x ~= hi + lo)
static __device__ __forceinline__ void cvt2(float x, unsigned short& h, unsigned short& l) {
  unsigned int u = __float_as_uint(x);
  unsigned int hb = (u + 0x7fffu + ((u >> 16) & 1u)) >> 16;
  h = (unsigned short)hb;
  float r = x - __uint_as_float(hb << 16);
  unsigned int u2 = __float_as_uint(r);
  l = (unsigned short)((u2 + 0x7fffu + ((u2 >> 16) & 1u)) >> 16);
}

// ---------- antialiased bilinear resize, all 4 stages in one launch ----------
__global__ void resize_all(const float* __restrict__ g, float* __restrict__ o0,
                           float* __restrict__ o1, float* __restrict__ o2,
                           float* __restrict__ o3) {
  int s = blockIdx.y;
  int h = 14 << s;                  // 14, 28, 56, 112
  float* out = (s == 0) ? o0 : (s == 1) ? o1 : (s == 2) ? o2 : o3;
  int inv_scale = GSZ / h;
  int w = h;
  int idx = blockIdx.x * blockDim.x + threadIdx.x;
  int total = BATCH * 3 * h * w;
  if (idx >= total) return;
  int j = idx % w; int t = idx / w;
  int i = t % h; t /= h;
  float ks = (float)inv_scale;
  float sy = (i + 0.5f) * ks - 0.5f;
  float sx = (j + 0.5f) * ks - 0.5f;
  int y0 = (int)ceilf(sy - ks); if (y0 < 0) y0 = 0;
  int y1 = (int)floorf(sy + ks); if (y1 > GSZ - 1) y1 = GSZ - 1;
  int x0 = (int)ceilf(sx - ks); if (x0 < 0) x0 = 0;
  int x1 = (int)floorf(sx + ks); if (x1 > GSZ - 1) x1 = GSZ - 1;
  const float* gp = g + (size_t)t * GSZ * GSZ;
  float wsx = 0.f;
  for (int x = x0; x <= x1; ++x) wsx += fmaxf(0.f, 1.f - fabsf(sx - (float)x) / ks);
  float acc = 0.f, wsy = 0.f;
  for (int y = y0; y <= y1; ++y) {
    float wy = fmaxf(0.f, 1.f - fabsf(sy - (float)y) / ks);
    wsy += wy;
    if (wy > 0.f) {
      const float* rp = gp + (size_t)y * GSZ;
      float row = 0.f;
      for (int x = x0; x <= x1; ++x) {
        float wx = fmaxf(0.f, 1.f - fabsf(sx - (float)x) / ks);
        row += wx * rp[x];
      }
      acc += wy * row;
    }
  }
  out[idx] = acc / (wsx * wsy);
}

// ---------- weight prep ----------
__global__ void prep_cw(const float* __restrict__ c0, const float* __restrict__ c1,
                        const float* __restrict__ c2, const float* __restrict__ c3,
                        float* __restrict__ cwT) {
  int s = blockIdx.y;
  const float* cw = (s == 0) ? c0 : (s == 1) ? c1 : (s == 2) ? c2 : c3;
  int idx = blockIdx.x * 256 + threadIdx.x;
  if (idx >= CINC * COMPC) return;
  int ci = idx >> 6, co = idx & 63;
  cwT[s * (CINC * COMPC) + idx] = cw[co * CINC + ci];
}

// ewT2 layout: [s][pos][ci][tap][12]  (k padded 9->12 for float4 alignment)
#define EW2_PER_S (4 * COMPC * 9 * 12)
__global__ void prep_ew(const float* __restrict__ e0, const float* __restrict__ e1,
                        const float* __restrict__ e2, const float* __restrict__ e3,
                        float* __restrict__ ewT2) {
  int s = blockIdx.y;
  const float* ew = (s == 0) ? e0 : (s == 1) ? e1 : (s == 2) ? e2 : e3;
  int idx = blockIdx.x * 256 + threadIdx.x;
  if (idx >= EW2_PER_S) return;
  int k = idx % 12; int r = idx / 12;
  int tap = r % 9; r /= 9;
  int ci = r % COMPC; int pos = r / COMPC;
  float val = 0.f;
  if (k < 9) val = ew[(size_t)(k * 4 + pos) * (COMPC * 9) + ci * 9 + tap];
  ewT2[(size_t)s * EW2_PER_S + idx] = val;
}

#define KPAD 416
__global__ void prep_w(const float* __restrict__ pw, short* __restrict__ Whi,
                       short* __restrict__ Wlo) {
  int idx = blockIdx.x * 256 + threadIdx.x;
  if (idx >= DIMC * KPAD) return;
  int co = idx / KPAD, k = idx % KPAD;
  float v = (k < CINC) ? pw[co * CINC + k] : 0.f;
  unsigned short hb = f2bf(v);
  Whi[idx] = (short)hb;
  Wlo[idx] = (short)f2bf(v - bf2f(hb));
}

// ---------- 1x1 conv 387->64 v3: thread = 1 px, 32 co; uniform s_load weights ----------
// src read 2x total (was 16x = 1.24 GB L3 at stage 4). Per ci: 1 VMEM + 8 scalar
// float4 (uniform -> s_load) + 32 FMA.
__global__ void comp_conv_kernel(const float* __restrict__ src, const float* __restrict__ g,
                                 const float* __restrict__ cwT, const float* __restrict__ cb,
                                 float* __restrict__ comp, int h, int w) {
  int hw = h * w;
  int p = blockIdx.x * 256 + threadIdx.x;
  if (p >= hw) return;
  int co0 = blockIdx.y * 32;
  int n = blockIdx.z;
  float acc[32];
  #pragma unroll
  for (int c = 0; c < 32; ++c) acc[c] = cb[co0 + c];
  const float* sp = src + (size_t)n * DIMC * hw + p;
  const float* wbase = cwT + co0;
  for (int ci = 0; ci < DIMC; ++ci) {
    float v = sp[(size_t)ci * hw];
    const float* wr = wbase + ci * COMPC;
    #pragma unroll
    for (int c = 0; c < 32; c += 4) {
      float4 wv = *(const float4*)(wr + c);
      acc[c] += wv.x * v; acc[c + 1] += wv.y * v;
      acc[c + 2] += wv.z * v; acc[c + 3] += wv.w * v;
    }
  }
  const float* gp = g + (size_t)n * 3 * hw + p;
  #pragma unroll
  for (int ci = 0; ci < 3; ++ci) {
    float v = gp[(size_t)ci * hw];
    const float* wr = wbase + (DIMC + ci) * COMPC;
    #pragma unroll
    for (int c = 0; c < 32; c += 4) {
      float4 wv = *(const float4*)(wr + c);
      acc[c] += wv.x * v; acc[c + 1] += wv.y * v;
      acc[c + 2] += wv.z * v; acc[c + 3] += wv.w * v;
    }
  }
  float* op = comp + (size_t)n * COMPC * hw + p;
  #pragma unroll
  for (int c = 0; c < 32; ++c) op[(size_t)(co0 + c) * hw] = acc[c];
}

// ---------- 3x3 conv 64->36 + pixel_shuffle + softmax, v3: 2-px strips ----------
// pos = blockIdx.y (uniform weights via aligned [pos][ci][tap][12] table -> s_load);
// 2-px strip keeps VMEM/px at 6 v-loads/ci while doubling block count vs 4-px.
__global__ void enc_mask_kernel(const float* __restrict__ comp, const float* __restrict__ ewT2,
                                const float* __restrict__ eb, float* __restrict__ mask,
                                int h, int w) {
  int hw = h * w;
  int sw2 = w >> 1;                 // w is even at every stage
  int nstrip = h * sw2;
  int strip = blockIdx.x * 256 + threadIdx.x;
  if (strip >= nstrip) return;
  int pos = blockIdx.y;
  int n = blockIdx.z;
  int i = strip / sw2;
  int j0 = (strip - i * sw2) * 2;
  float acc[2][9];
  #pragma unroll
  for (int k = 0; k < 9; ++k) {
    float bv = eb[k * 4 + pos];
    acc[0][k] = bv; acc[1][k] = bv;
  }
  const float* cpn = comp + (size_t)n * COMPC * hw;
  const float* wpos = ewT2 + (size_t)pos * COMPC * 9 * 12;
  for (int ci = 0; ci < COMPC; ++ci) {
    const float* cp = cpn + (size_t)ci * hw;
    float v[3][4];
    #pragma unroll
    for (int di = 0; di < 3; ++di) {
      int y = i + di - 1;
      bool yok = (y >= 0 && y < h);
      #pragma unroll
      for (int xx = 0; xx < 4; ++xx) {
        int x = j0 - 1 + xx;
        v[di][xx] = (yok && x >= 0 && x < w) ? cp[(size_t)y * w + x] : 0.f;
      }
    }
    const float* wb = wpos + (size_t)ci * 9 * 12;
    #pragma unroll
    for (int tap = 0; tap < 9; ++tap) {
      int di = tap / 3, dj = tap % 3;
      float4 wa = *(const float4*)(wb + tap * 12);
      float4 wc = *(const float4*)(wb + tap * 12 + 4);
      float w8 = wb[tap * 12 + 8];
      #pragma unroll
      for (int px = 0; px < 2; ++px) {
        float val = v[di][dj + px];
        acc[px][0] += wa.x * val; acc[px][1] += wa.y * val;
        acc[px][2] += wa.z * val; acc[px][3] += wa.w * val;
        acc[px][4] += wc.x * val; acc[px][5] += wc.y * val;
        acc[px][6] += wc.z * val; acc[px][7] += wc.w * val;
        acc[px][8] += w8 * val;
      }
    }
  }
  int pp = pos >> 1, q = pos & 1;
  int H = 2 * h, W = 2 * w;
  #pragma unroll
  for (int px = 0; px < 2; ++px) {
    int jj = j0 + px;
    float m = -1e30f;
    #pragma unroll
    for (int k = 0; k < 9; ++k) m = fmaxf(m, acc[px][k]);
    float e[9]; float s = 0.f;
    #pragma unroll
    for (int k = 0; k < 9; ++k) { e[k] = __expf(acc[px][k] - m); s += e[k]; }
    float inv = 1.f / s;
    float* mp = mask + (((size_t)n * H + (2 * i + pp)) * W + (2 * jj + q)) * 9;
    #pragma unroll
    for (int k = 0; k < 9; ++k) mp[k] = e[k] * inv;
  }
}

// ---------- CARAFE reassembly: 48 channels per block (mask re-read 8x, was 24x) ----------
__global__ void carafe_kernel(const float* __restrict__ src, const float* __restrict__ mask,
                              float* __restrict__ out, int h, int w) {
  int p = blockIdx.x * blockDim.x + threadIdx.x;
  int hw = h * w;
  if (p >= hw) return;
  int c0 = blockIdx.y * 48, n = blockIdx.z;
  int i = p / w, j = p % w;
  int H = 2 * h, W = 2 * w;
  float m[4][9];
  #pragma unroll
  for (int pp = 0; pp < 2; ++pp)
    #pragma unroll
    for (int q = 0; q < 2; ++q) {
      const float* mp = mask + (((size_t)n * H + (2 * i + pp)) * W + (2 * j + q)) * 9;
      #pragma unroll
      for (int k = 0; k < 9; ++k) m[pp * 2 + q][k] = mp[k];
    }
  for (int cc = 0; cc < 48; ++cc) {
    int c = c0 + cc;
    const float* sp = src + ((size_t)(n * DIMC + c)) * hw;
    float v[9];
    #pragma unroll
    for (int k = 0; k < 9; ++k) {
      int y = i - 1 + k / 3, x = j - 1 + k % 3;
      v[k] = (y >= 0 && y < h && x >= 0 && x < w) ? sp[(size_t)y * w + x] : 0.f;
    }
    float* op = out + ((size_t)(n * DIMC + c)) * H * W;
    #pragma unroll
    for (int pp = 0; pp < 2; ++pp) {
      float a0 = 0.f, a1 = 0.f;
      #pragma unroll
      for (int k = 0; k < 9; ++k) {
        a0 += v[k] * m[pp * 2 + 0][k];
        a1 += v[k] * m[pp * 2 + 1][k];
      }
      float2 r; r.x = a0; r.y = a1;
      *(float2*)(op + (size_t)(2 * i + pp) * W + 2 * j) = r;
    }
  }
}

// ---------- final 1x1 conv 387->384 via bf16x3 MFMA, v4 ----------
// v3 post-mortem: __syncthreads() = s_waitcnt vmcnt(0)+s_barrier -> drains the X
// prefetch EVERY kt (HBM latency back on critical path); weight L2 latency exposed
// in-loop. v4 (T3/T4-lite): raw s_barrier + lgkmcnt(0) only (prefetches stay in
// flight across barriers, compiler emits counted vmcnt for deps); weights reg-
// prefetched depth-1; kt fully unrolled so double-buffer regs SSA-rename.
__global__ __launch_bounds__(512, 4) void final_conv_mfma4(
    const float* __restrict__ guid, const short* __restrict__ Whi,
    const short* __restrict__ Wlo, const float* __restrict__ pb,
    float* __restrict__ out) {
  __shared__ short XH[2][2048];
  __shared__ short XL[2][2048];
  const int HW = GSZ * GSZ;
  const int n = blockIdx.y;
  const int px0 = blockIdx.x * 64;
  const int tid = threadIdx.x;
  const int wv = tid >> 6;
  const int lane = tid & 63;
  const int lm = lane & 15, qq = lane >> 4;

  // staging map: thread (wv, lane) stages element (k_local = wv*4+i, px = lane)
  const int s_nt = lane >> 4, s_lm = lane & 15;
  const int s_qq = wv >> 1;
  const int s_jh = (wv & 1) * 4;
  const int waddr = ((s_nt * 4 + s_qq) * 16 + s_lm) * 8 + s_jh;

  const float* Xb = out + (size_t)n * DIMC * HW + px0 + lane;
  const float* Gb = guid + (size_t)n * 3 * HW + px0 + lane;

  f32x4 acc[3][4];
  #pragma unroll
  for (int mt = 0; mt < 3; ++mt)
    #pragma unroll
    for (int nt = 0; nt < 4; ++nt) acc[mt][nt] = (f32x4){0.f, 0.f, 0.f, 0.f};

  // prologue: chunk 0 -> buf0; chunk 1 -> nvA; W(0) -> regs
  float nvA[4];
  bf16x8 ahC[3], alC[3];
  {
    unsigned short hs[4], ls[4];
    #pragma unroll
    for (int i = 0; i < 4; ++i) {
      float v = Xb[(size_t)(wv * 4 + i) * HW];
      cvt2(v, hs[i], ls[i]);
    }
    *(s16x4*)&XH[0][waddr] = (s16x4){(short)hs[0], (short)hs[1], (short)hs[2], (short)hs[3]};
    *(s16x4*)&XL[0][waddr] = (s16x4){(short)ls[0], (short)ls[1], (short)ls[2], (short)ls[3]};
    #pragma unroll
    for (int i = 0; i < 4; ++i) nvA[i] = Xb[(size_t)(32 + wv * 4 + i) * HW];
    #pragma unroll
    for (int mt = 0; mt < 3; ++mt) {
      int co = wv * 48 + mt * 16 + lm;
      size_t woff = (size_t)co * KPAD + qq * 8;
      ahC[mt] = *(const bf16x8*)(Whi + woff);
      alC[mt] = *(const bf16x8*)(Wlo + woff);
    }
  }
  __syncthreads();   // one full drain in the prologue is fine

  #pragma unroll
  for (int kt = 0; kt < 13; ++kt) {
    const int cur = kt & 1;
    // ---- issue weight prefetch for kt+1 (retires across the barrier) ----
    bf16x8 ahN[3], alN[3];
    if (kt < 12) {
      #pragma unroll
      for (int mt = 0; mt < 3; ++mt) {
        int co = wv * 48 + mt * 16 + lm;
        size_t woff = (size_t)co * KPAD + (kt + 1) * 32 + qq * 8;
        ahN[mt] = *(const bf16x8*)(Whi + woff);
        alN[mt] = *(const bf16x8*)(Wlo + woff);
      }
    }
    // ---- issue X prefetch for chunk kt+2 ----
    float nvB[4] = {0.f, 0.f, 0.f, 0.f};
    if (kt <= 10) {
      int kb = (kt + 2) * 32 + wv * 4;
      if (kt < 10) {
        #pragma unroll
        for (int i = 0; i < 4; ++i) nvB[i] = Xb[(size_t)(kb + i) * HW];
      } else {  // chunk 12: guidance rows 384..386 + zero pad
        #pragma unroll
        for (int i = 0; i < 4; ++i) {
          int k = kb + i;
          nvB[i] = (k < CINC) ? Gb[(size_t)(k - DIMC) * HW] : 0.f;
        }
      }
    }
    // ---- MFMA: nt-outer so only one bh/bl pair is live (VGPR) ----
    #pragma unroll
    for (int nt = 0; nt < 4; ++nt) {
      int a = ((nt * 4 + qq) * 16 + lm) * 8;
      bf16x8 bh = *(const bf16x8*)&XH[cur][a];
      bf16x8 bl = *(const bf16x8*)&XL[cur][a];
      #pragma unroll
      for (int mt = 0; mt < 3; ++mt) {
        acc[mt][nt] = __builtin_amdgcn_mfma_f32_16x16x32_bf16(ahC[mt], bh, acc[mt][nt], 0, 0, 0);
        acc[mt][nt] = __builtin_amdgcn_mfma_f32_16x16x32_bf16(ahC[mt], bl, acc[mt][nt], 0, 0, 0);
        acc[mt][nt] = __builtin_amdgcn_mfma_f32_16x16x32_bf16(alC[mt], bh, acc[mt][nt], 0, 0, 0);
      }
    }
    // ---- convert + write chunk kt+1 into the other buffer ----
    if (kt <= 11) {
      unsigned short hs[4], ls[4];
      #pragma unroll
      for (int i = 0; i < 4; ++i) cvt2(nvA[i], hs[i], ls[i]);
      *(s16x4*)&XH[cur ^ 1][waddr] = (s16x4){(short)hs[0], (short)hs[1], (short)hs[2], (short)hs[3]};
      *(s16x4*)&XL[cur ^ 1][waddr] = (s16x4){(short)ls[0], (short)ls[1], (short)ls[2], (short)ls[3]};
    }
    // raw barrier: drain LDS ops only; global prefetches stay in flight
    asm volatile("s_waitcnt lgkmcnt(0)" ::: "memory");
    __builtin_amdgcn_s_barrier();
    __builtin_amdgcn_sched_barrier(0);
    #pragma unroll
    for (int i = 0; i < 4; ++i) nvA[i] = nvB[i];
    if (kt < 12) {
      #pragma unroll
      for (int mt = 0; mt < 3; ++mt) { ahC[mt] = ahN[mt]; alC[mt] = alN[mt]; }
    }
  }

  #pragma unroll
  for (int mt = 0; mt < 3; ++mt) {
    #pragma unroll
    for (int nt = 0; nt < 4; ++nt) {
      #pragma unroll
      for (int r = 0; r < 4; ++r) {
        int co = wv * 48 + mt * 16 + qq * 4 + r;
        int px = px0 + nt * 16 + lm;
        out[((size_t)(n * DIMC + co)) * HW + px] = acc[mt][nt][r] + pb[co];
      }
    }
  }
}

extern "C" void kernel_launch(void* const* d_in, const int* in_sizes, int n_in,
                              void* d_out, int out_size, void* d_ws, size_t ws_size,
                              hipStream_t stream) {
  const float* source   = (const float*)d_in[0];
  const float* guidance = (const float*)d_in[1];
  const float* cw[4] = {(const float*)d_in[2],  (const float*)d_in[6],
                        (const float*)d_in[10], (const float*)d_in[14]};
  const float* cb[4] = {(const float*)d_in[3],  (const float*)d_in[7],
                        (const float*)d_in[11], (const float*)d_in[15]};
  const float* ew[4] = {(const float*)d_in[4],  (const float*)d_in[8],
                        (const float*)d_in[12], (const float*)d_in[16]};
  const float* eb[4] = {(const float*)d_in[5],  (const float*)d_in[9],
                        (const float*)d_in[13], (const float*)d_in[17]};
  const float* pw = (const float*)d_in[18];
  const float* pb = (const float*)d_in[19];
  float* out = (float*)d_out;

  float* ws = (float*)d_ws;
  float* g14  = ws;                         // 4*3*14*14   = 2352
  float* g28  = g14 + 2352;                 // 4*3*28*28   = 9408
  float* g56  = g28 + 9408;                 // 4*3*56*56   = 37632
  float* g112 = g56 + 37632;                // 4*3*112*112 = 150528
  float* comp_buf = g112 + 150528;          // 4*64*112*112  = 3211264
  float* mask_buf = comp_buf + 3211264;     // 4*224*224*9   = 1806336
  float* s2  = mask_buf + 1806336;          // 4*384*28*28   = 1204224
  float* s4  = s2 + 1204224;                // 4*384*56*56   = 4816896
  float* s8  = s4 + 4816896;                // 4*384*112*112 = 19267584
  float* cwT = s8 + 19267584;               // 4*387*64      = 99072
  float* ewT2 = cwT + 99072;                // 4*27648       = 110592
  short* Whi = (short*)(ewT2 + 110592);     // 384*416 shorts
  short* Wlo = Whi + DIMC * KPAD;

  prep_cw<<<dim3((CINC * COMPC + 255) / 256, 4), 256, 0, stream>>>(cw[0], cw[1], cw[2], cw[3], cwT);
  prep_ew<<<dim3((EW2_PER_S + 255) / 256, 4), 256, 0, stream>>>(ew[0], ew[1], ew[2], ew[3], ewT2);
  prep_w<<<(DIMC * KPAD + 255) / 256, 256, 0, stream>>>(pw, Whi, Wlo);
  resize_all<<<dim3((BATCH * 3 * 112 * 112 + 255) / 256, 4), 256, 0, stream>>>(
      guidance, g14, g28, g56, g112);

  const float* srcs[4] = {source, s2, s4, s8};
  float* outs[4] = {s2, s4, s8, out};
  float* gbufs[4] = {g14, g28, g56, g112};
  const int hs[4] = {14, 28, 56, 112};
  for (int s = 0; s < 4; ++s) {
    int h = hs[s], w = h, hw = h * w;
    int sw2 = w / 2;
    comp_conv_kernel<<<dim3((hw + 255) / 256, 2, BATCH), 256, 0, stream>>>(
        srcs[s], gbufs[s], cwT + s * (CINC * COMPC), cb[s], comp_buf, h, w);
    enc_mask_kernel<<<dim3((h * sw2 + 255) / 256, 4, BATCH), 256, 0, stream>>>(
        comp_buf, ewT2 + (size_t)s * EW2_PER_S, eb[s], mask_buf, h, w);
    carafe_kernel<<<dim3((hw + 255) / 256, DIMC / 48, BATCH), 256, 0, stream>>>(
        srcs[s], mask_buf, outs[s], h, w);
  }
  final_conv_mfma4<<<dim3((GSZ * GSZ) / 64, BATCH), 512, 0, stream>>>(guidance, Whi, Wlo, pb, out);
}